// Round 4
// baseline (310.223 us; speedup 1.0000x reference)
//
#include <hip/hip_runtime.h>
#include <stdint.h>

#define Bq 8
#define Mq 1024
#define Hq 512
#define NHq 8
#define Dq 64
#define SPANq 1024
#define MKq 2048
#define PR2 104   // attn P-row stride (ushorts); 96 used (chunk=64: window 80 + zero pad to 96)

typedef __bf16 bf16x8 __attribute__((ext_vector_type(8)));
typedef _Float16 f16x8 __attribute__((ext_vector_type(8)));
typedef float f32x4 __attribute__((ext_vector_type(4)));
typedef unsigned short ushort8 __attribute__((ext_vector_type(8)));
typedef unsigned int uint2v __attribute__((ext_vector_type(2)));

static __device__ __forceinline__ unsigned short f2bf(float f) {
  union { float f; unsigned u; } x; x.f = f;
  unsigned r = x.u + 0x7FFFu + ((x.u >> 16) & 1u);
  return (unsigned short)(r >> 16);
}

static __device__ __forceinline__ unsigned pk_f16(float a, float b) {
  return __builtin_bit_cast(unsigned, __builtin_amdgcn_cvt_pkrtz(a, b));
}

static __device__ __forceinline__ f32x4 mfma_bf16(bf16x8 a, bf16x8 b, f32x4 c) {
  return __builtin_amdgcn_mfma_f32_16x16x32_bf16(a, b, c, 0, 0, 0);
}
static __device__ __forceinline__ f32x4 mfma_f16(f16x8 a, f16x8 b, f32x4 c) {
  return __builtin_amdgcn_mfma_f32_16x16x32_f16(a, b, c, 0, 0, 0);
}

// async 16B/lane global->LDS DMA; lds dest = uniform base + lane*16
static __device__ __forceinline__ void async_ld16(const void* g, void* l) {
  __builtin_amdgcn_global_load_lds(
      (const __attribute__((address_space(1))) void*)g,
      (__attribute__((address_space(3))) void*)l, 16, 0, 0);
}

// ---------------- elementwise fp32 -> bf16 for q/k/v
__global__ __launch_bounds__(256) void conv_bf16(
    const float* __restrict__ q, const float* __restrict__ k,
    const float* __restrict__ v, unsigned short* __restrict__ qo,
    unsigned short* __restrict__ ko, unsigned short* __restrict__ vo) {
  const int z = blockIdx.y;
  const float* src = (z == 0) ? q : (z == 1) ? k : v;
  unsigned short* dst = (z == 0) ? qo : (z == 1) ? ko : vo;
  const int n = (z == 0) ? (Bq * Mq * Hq) : (Bq * MKq * Hq);
  const int idx = (blockIdx.x * 256 + threadIdx.x) * 8;
  if (idx >= n) return;
  const f32x4 f0 = *(const f32x4*)(src + idx);
  const f32x4 f1 = *(const f32x4*)(src + idx + 4);
  ushort8 h;
  h[0] = f2bf(f0[0]); h[1] = f2bf(f0[1]); h[2] = f2bf(f0[2]); h[3] = f2bf(f0[3]);
  h[4] = f2bf(f1[0]); h[5] = f2bf(f1[1]); h[6] = f2bf(f1[2]); h[7] = f2bf(f1[3]);
  *(ushort8*)(dst + idx) = h;
}

// ---------------- prep: transpose+convert weights (WT[o][i]=W[i][o]) and pos (posT[s][d]=pos[d][s])
__global__ __launch_bounds__(256) void prep_transpose(
    const float* __restrict__ Wq, const float* __restrict__ Wk,
    const float* __restrict__ Wv, const float* __restrict__ Wo,
    const float* __restrict__ pos,
    unsigned short* __restrict__ WTq, unsigned short* __restrict__ WTk,
    unsigned short* __restrict__ WTv, unsigned short* __restrict__ WTo,
    unsigned short* __restrict__ posT) {
  __shared__ float tile[64][65];
  const int bid = blockIdx.x;
  const float* src; unsigned short* dst;
  int src_stride, dst_stride, i0, o0;
  if (bid < 256) {
    const int w = bid >> 6, t = bid & 63;
    src = (w == 0) ? Wq : (w == 1) ? Wk : (w == 2) ? Wv : Wo;
    dst = (w == 0) ? WTq : (w == 1) ? WTk : (w == 2) ? WTv : WTo;
    src_stride = Hq; dst_stride = Hq;
    i0 = (t >> 3) * 64; o0 = (t & 7) * 64;
  } else {
    const int t = bid - 256;
    src = pos; dst = posT;
    src_stride = SPANq; dst_stride = Dq;
    i0 = 0; o0 = t * 64;
  }
  const int tid = threadIdx.x;
  for (int e = tid; e < 4096; e += 256) {
    const int r = e >> 6, c = e & 63;
    tile[r][c] = src[(size_t)(i0 + r) * src_stride + o0 + c];
  }
  __syncthreads();
  for (int e = tid; e < 4096; e += 256) {
    const int r = e >> 6, c = e & 63;
    dst[(size_t)(o0 + r) * dst_stride + i0 + c] = f2bf(tile[c][r]);
  }
}

// ---------------- 128x128 GEMM body via global_load_lds staging (BK=64, XOR-swizzled)
// C[r][c] = sum_k Xb[r][k] * WT[c][k]
// mode 0: -> outb[(b*8+head)*T + t][d]  bf16
// mode 2: -> vT[(b*8+head)*64 + d][t]   f16 (LDS-transposed epilogue)
// mode 3: -> outf fp32 row-major
static __device__ __forceinline__ void gemm_body(
    const unsigned short* __restrict__ Xb, const unsigned short* __restrict__ WT,
    unsigned short* __restrict__ outb, _Float16* __restrict__ outv,
    float* __restrict__ outf, int mode, int tshift, int bx, int by,
    unsigned short* sh) {
  unsigned short* As = sh;               // [128][64] unpadded, swizzled
  unsigned short* Bs = sh + 8192;
  const int tid = threadIdx.x;
  const int wave = tid >> 6, lane = tid & 63;
  const int q = lane >> 4, l16 = lane & 15;
  const int wy = wave >> 1, wx = wave & 1;
  const size_t m0 = (size_t)bx * 128;
  const int n0 = by * 128;
  const int dsub = lane >> 3;                 // row offset within slot
  const int dswz = (lane & 7) ^ dsub;         // swizzled source chunk

  f32x4 acc[4][4] = {};

  for (int k0 = 0; k0 < Hq; k0 += 64) {
    __syncthreads();
#pragma unroll
    for (int i = 0; i < 4; i++) {
      const int s = wave * 4 + i;             // slot 0..15, 8 rows each
      const int r = s * 8 + dsub;             // row 0..127
      async_ld16(Xb + (m0 + r) * Hq + k0 + dswz * 8, As + s * 512);
      async_ld16(WT + (size_t)(n0 + r) * Hq + k0 + dswz * 8, Bs + s * 512);
    }
    __syncthreads();
    bf16x8 af[2][4], bg[2][4];
#pragma unroll
    for (int h = 0; h < 2; h++) {
#pragma unroll
      for (int mt = 0; mt < 4; mt++) {
        const int R = wy * 64 + mt * 16 + l16;
        af[h][mt] = *(const bf16x8*)(As + R * 64 + (((h * 4 + q) ^ (l16 & 7)) * 8));
      }
#pragma unroll
      for (int nt = 0; nt < 4; nt++) {
        const int R = wx * 64 + nt * 16 + l16;
        bg[h][nt] = *(const bf16x8*)(Bs + R * 64 + (((h * 4 + q) ^ (l16 & 7)) * 8));
      }
    }
#pragma unroll
    for (int h = 0; h < 2; h++)
#pragma unroll
      for (int mt = 0; mt < 4; mt++)
#pragma unroll
        for (int nt = 0; nt < 4; nt++)
          acc[mt][nt] = mfma_bf16(af[h][mt], bg[h][nt], acc[mt][nt]);
  }

  if (mode == 2) {
    __syncthreads();  // protect tile LDS before reuse
    // transpose epilogue: per-wave 64x64 tile -> vT[(b*8+head)*64 + d][t] f16
    _Float16* tr = (_Float16*)sh + wave * 4608;  // [64][72]
#pragma unroll
    for (int nt = 0; nt < 4; nt++)
#pragma unroll
      for (int mt = 0; mt < 4; mt++)
#pragma unroll
        for (int r = 0; r < 4; r++)
          tr[(nt * 16 + l16) * 72 + mt * 16 + q * 4 + r] = (_Float16)acc[mt][nt][r];
    const int head = by * 2 + wx;
    const int mrow0 = (int)m0 + wy * 64;
    const int Tlen = 1 << tshift;
    const int b = mrow0 >> tshift, t0 = mrow0 & (Tlen - 1);
#pragma unroll
    for (int it = 0; it < 8; it++) {
      const int dl = it * 8 + (lane >> 3), tl = (lane & 7) * 8;
      const f16x8 v = *(const f16x8*)(tr + dl * 72 + tl);
      *(f16x8*)(outv + ((size_t)((b * 8 + head) * 64 + dl)) * Tlen + t0 + tl) = v;
    }
    return;
  }

  const int Tlen = 1 << tshift;
#pragma unroll
  for (int mt = 0; mt < 4; mt++) {
#pragma unroll
    for (int nt = 0; nt < 4; nt++) {
      const int c = n0 + wx * 64 + nt * 16 + l16;
#pragma unroll
      for (int r = 0; r < 4; r++) {
        const int m = (int)m0 + wy * 64 + mt * 16 + q * 4 + r;
        const float val = acc[mt][nt][r];
        if (mode == 3) {
          outf[(size_t)m * Hq + c] = val;
        } else {
          const int b = m >> tshift, t = m & (Tlen - 1);
          const int head = c >> 6, d = c & 63;
          outb[(((size_t)(b * 8 + head) << tshift) + t) * 64 + d] = f2bf(val);
        }
      }
    }
  }
}

__global__ __launch_bounds__(256, 2) void gemm128(
    const unsigned short* __restrict__ Xb, const unsigned short* __restrict__ WT,
    unsigned short* __restrict__ outb, _Float16* __restrict__ outv,
    float* __restrict__ outf, int mode, int tshift) {
  __shared__ unsigned short sh[18432];   // 36 KB
  gemm_body(Xb, WT, outb, outv, outf, mode, tshift, blockIdx.x, blockIdx.y, sh);
}

// merged Q/K/V projection launch: grid (320, 4); x<64 -> Q, x<192 -> K, else -> V.
// Each GEMM alone is 256-512 blocks (1-2 blocks/CU on 256 CUs, grid-starved);
// merged = 1280 blocks fills the machine and removes two launch gaps.
__global__ __launch_bounds__(256, 2) void gemm_qkv(
    const unsigned short* __restrict__ qX, const unsigned short* __restrict__ kX,
    const unsigned short* __restrict__ vX,
    const unsigned short* __restrict__ WTq, const unsigned short* __restrict__ WTk,
    const unsigned short* __restrict__ WTv,
    unsigned short* __restrict__ qb, unsigned short* __restrict__ kbuf,
    _Float16* __restrict__ vTb) {
  __shared__ unsigned short sh[18432];   // 36 KB
  const int x = blockIdx.x;
  const unsigned short* Xb; const unsigned short* WT;
  unsigned short* outb = nullptr; _Float16* outv = nullptr;
  int mode, tshift, bx;
  if (x < 64)       { Xb = qX; WT = WTq; outb = qb;   mode = 0; tshift = 10; bx = x; }
  else if (x < 192) { Xb = kX; WT = WTk; outb = kbuf; mode = 0; tshift = 11; bx = x - 64; }
  else              { Xb = vX; WT = WTv; outv = vTb;  mode = 2; tshift = 11; bx = x - 192; }
  gemm_body(Xb, WT, outb, outv, nullptr, mode, tshift, bx, blockIdx.y, sh);
}

// ---------------- banded attention: LDS-staged K+pos, chunk=64 keys.
// LDS = Kt 16K + Pt 8K + Psh 13K = 37 KB -> 4 blocks/CU (16 waves/CU, 4/SIMD) for
// latency hiding; grid 1024 = exactly 4 blocks/CU, zero tail. 16 chunks x 2 barriers.
// block = 64 queries x one head; wave owns 16 queries; lane owns row m=lane&15.
__global__ __launch_bounds__(256, 4) void attn3(
    const unsigned short* __restrict__ qb, const unsigned short* __restrict__ kglob,
    const _Float16* __restrict__ vT, const unsigned short* __restrict__ posT,
    unsigned short* __restrict__ ctx) {
  __shared__ unsigned short Kt[8192];           // K tile: 128 rows x 64 d (swizzled)
  __shared__ unsigned short Pt[4096];           // pos tile: 64 rows x 64 d (swizzled)
  __shared__ unsigned short Psh[4 * 16 * PR2];  // P / pos-skew rows (wave-private)

  const int tid = threadIdx.x;
  const int wave = tid >> 6, lane = tid & 63;
  const int q = lane >> 4, l16 = lane & 15;
  const int n = blockIdx.y;
  const int m0 = blockIdx.x * 64;
  const int m0w = m0 + wave * 16;
  const int dsub = lane >> 3;
  const int dswz = (lane & 7) ^ dsub;

  unsigned short* row = Psh + (wave * 16 + l16) * PR2;

  // Q fragments (B-operand): col m = l16, k = q*8+j over d
  const unsigned short* qbase = qb + ((size_t)n * Mq + m0w + l16) * Dq;
  const bf16x8 qf0 = *(const bf16x8*)(qbase + q * 8);
  const bf16x8 qf1 = *(const bf16x8*)(qbase + 32 + q * 8);

  const unsigned short* kbn = kglob + (size_t)n * MKq * Dq;
  const _Float16* vbn = vT + (size_t)n * Dq * MKq;

  f32x4 O[4] = {};
  float zrow = 0.f, mrow = -1e30f;

  for (int c = 0; c < 16; c++) {
    const int sbase = c * 64;
    const int jb = m0 + sbase;       // K tile base row (block-level)
    const int j00 = m0w + sbase;     // wave's base

    __syncthreads();  // previous chunk's tile reads complete
    // --- DMA K tile: 16 slots x 1 KB; pos tile: 8 slots
#pragma unroll
    for (int i = 0; i < 4; i++) {
      const int s = wave + 4 * i;
      const int r = s * 8 + dsub;    // 0..127
      async_ld16(kbn + (size_t)(jb + r) * Dq + dswz * 8, Kt + s * 512);
    }
#pragma unroll
    for (int i = 0; i < 2; i++) {
      const int s = wave + 4 * i;
      const int r = s * 8 + dsub;    // 0..63
      async_ld16(posT + (size_t)(sbase + r) * Dq + dswz * 8, Pt + s * 512);
    }
    __syncthreads();  // DMA drained (compiler emits vmcnt(0) before barrier)

    // --- pos logits -> skewed rows: col = 16 + s_local + m
#pragma unroll
    for (int t = 0; t < 4; t++) {
      const int rl = t * 16 + l16;
      const int ch = (q ^ (l16 & 7)) * 8;
      const bf16x8 p0 = *(const bf16x8*)(Pt + rl * 64 + ch);
      const bf16x8 p1 = *(const bf16x8*)(Pt + rl * 64 + (ch ^ 32));
      f32x4 b = {};
      b = mfma_bf16(p0, qf0, b);
      b = mfma_bf16(p1, qf1, b);
      const int cw = 16 + t * 16 + 4 * q + l16;
      row[cw + 0] = f2bf(b[0]);
      row[cw + 1] = f2bf(b[1]);
      row[cw + 2] = f2bf(b[2]);
      row[cw + 3] = f2bf(b[3]);
    }

    // --- ctx logits S^T[j][m] from K tile + skewed pos readback + band masks
    f32x4 S[5];
#pragma unroll
    for (int t = 0; t < 5; t++) {
      const int rl = wave * 16 + t * 16 + l16;  // 0..127
      const int ch = (q ^ (l16 & 7)) * 8;
      const bf16x8 k0 = *(const bf16x8*)(Kt + rl * 64 + ch);
      const bf16x8 k1 = *(const bf16x8*)(Kt + rl * 64 + (ch ^ 32));
      f32x4 a = {};
      a = mfma_bf16(k0, qf0, a);
      a = mfma_bf16(k1, qf1, a);
      const uint2v pv = *(const uint2v*)(row + 16 + t * 16 + 4 * q);
      a[0] += __uint_as_float(pv.x << 16);
      a[1] += __uint_as_float(pv.x & 0xffff0000u);
      a[2] += __uint_as_float(pv.y << 16);
      a[3] += __uint_as_float(pv.y & 0xffff0000u);
      S[t] = a;
    }
#pragma unroll
    for (int r = 0; r < 4; r++) {
      if (4 * q + r < l16) S[0][r] = -1e30f;
      if (4 * q + r >= l16) S[4][r] = -1e30f;
    }

    // --- online softmax in registers
    float mx = -1e30f;
#pragma unroll
    for (int t = 0; t < 5; t++)
      mx = fmaxf(mx, fmaxf(fmaxf(S[t][0], S[t][1]), fmaxf(S[t][2], S[t][3])));
    mx = fmaxf(mx, __shfl_xor(mx, 16, 64));
    mx = fmaxf(mx, __shfl_xor(mx, 32, 64));
    const float m_new = fmaxf(mrow, mx);
    const float alpha = __expf((mrow - m_new) * 0.125f);
    float zs = 0.f;
#pragma unroll
    for (int t = 0; t < 5; t++) {
#pragma unroll
      for (int r = 0; r < 4; r++) {
        const float e = __expf((S[t][r] - m_new) * 0.125f);
        S[t][r] = e; zs += e;
      }
    }
    zs += __shfl_xor(zs, 16, 64);
    zs += __shfl_xor(zs, 32, 64);
    zrow = zrow * alpha + zs;
    mrow = m_new;
#pragma unroll
    for (int dt = 0; dt < 4; dt++) O[dt] *= alpha;

    // --- P -> LDS f16 at [m][j_local]; zero tail [80,96)
#pragma unroll
    for (int t = 0; t < 5; t++) {
      *(unsigned*)(row + t * 16 + 4 * q) = pk_f16(S[t][0], S[t][1]);
      *(unsigned*)(row + t * 16 + 4 * q + 2) = pk_f16(S[t][2], S[t][3]);
    }
    *(unsigned*)(row + 80 + 4 * q) = 0u;
    *(unsigned*)(row + 80 + 4 * q + 2) = 0u;

    // --- PV: O^T += V^T . P^T  (V direct from global; batch all 12 loads)
    f16x8 Bf[3];
#pragma unroll
    for (int kt = 0; kt < 3; kt++)
      Bf[kt] = *(const f16x8*)(row + kt * 32 + q * 8);
    f16x8 Vv[3][4];
#pragma unroll
    for (int kt = 0; kt < 3; kt++) {
      int j = j00 + kt * 32 + q * 8;
      if (j > MKq - 8) j = MKq - 8;  // clamped cols have P==0
#pragma unroll
      for (int dt = 0; dt < 4; dt++)
        Vv[kt][dt] = *(const f16x8*)(vbn + (size_t)(dt * 16 + l16) * MKq + j);
    }
#pragma unroll
    for (int kt = 0; kt < 3; kt++)
#pragma unroll
      for (int dt = 0; dt < 4; dt++)
        O[dt] = mfma_f16(Vv[kt][dt], Bf[kt], O[dt]);
  }

  // epilogue: ctx[b*M + m][head*64 + d] = O/Z  (lane owns row m = l16)
  const float zi = 1.f / zrow;
  unsigned short* cp = ctx + ((size_t)(n >> 3) * Mq + m0w + l16) * Hq + (n & 7) * Dq;
#pragma unroll
  for (int dt = 0; dt < 4; dt++)
#pragma unroll
    for (int r = 0; r < 4; r++)
      cp[dt * 16 + q * 4 + r] = f2bf(O[dt][r] * zi);
}

extern "C" void kernel_launch(void* const* d_in, const int* in_sizes, int n_in,
                              void* d_out, int out_size, void* d_ws, size_t ws_size,
                              hipStream_t stream) {
  const float* query = (const float*)d_in[0];
  const float* key   = (const float*)d_in[1];
  const float* value = (const float*)d_in[2];
  const float* pos   = (const float*)d_in[3];
  const float* Wq    = (const float*)d_in[4];
  const float* Wk    = (const float*)d_in[5];
  const float* Wv    = (const float*)d_in[6];
  const float* Wo    = (const float*)d_in[7];
  float* out = (float*)d_out;

  char* w = (char*)d_ws;
  unsigned short* qX   = (unsigned short*)w; w += (size_t)Bq * Mq * Hq * 2;    // 8 MB
  unsigned short* kX   = (unsigned short*)w; w += (size_t)Bq * MKq * Hq * 2;   // 16 MB
  unsigned short* vX   = (unsigned short*)w; w += (size_t)Bq * MKq * Hq * 2;   // 16 MB
  unsigned short* qb   = (unsigned short*)w; w += (size_t)64 * Mq * Dq * 2;    // 8 MB
  unsigned short* kbuf = (unsigned short*)w; w += (size_t)64 * MKq * Dq * 2;   // 16 MB
  _Float16*       vTb  = (_Float16*)w;       w += (size_t)64 * Dq * MKq * 2;   // 16 MB
  unsigned short* posT = (unsigned short*)w; w += (size_t)SPANq * Dq * 2;      // 128 KB
  unsigned short* WTq  = (unsigned short*)w; w += (size_t)Hq * Hq * 2;
  unsigned short* WTk  = (unsigned short*)w; w += (size_t)Hq * Hq * 2;
  unsigned short* WTv  = (unsigned short*)w; w += (size_t)Hq * Hq * 2;
  unsigned short* WTo  = (unsigned short*)w; w += (size_t)Hq * Hq * 2;
  unsigned short* ctx  = (unsigned short*)w; w += (size_t)Bq * Mq * Hq * 2;    // 8 MB

  prep_transpose<<<272, 256, 0, stream>>>(Wq, Wk, Wv, Wo, pos, WTq, WTk, WTv, WTo, posT);
  conv_bf16<<<dim3(4096, 3), 256, 0, stream>>>(query, key, value, qX, kX, vX);
  gemm_qkv<<<dim3(320, 4), 256, 0, stream>>>(qX, kX, vX, WTq, WTk, WTv, qb, kbuf, vTb);
  attn3<<<dim3(16, 64), 256, 0, stream>>>(qb, kbuf, vTb, posT, ctx);
  gemm128<<<dim3(64, 4), 256, 0, stream>>>(ctx, WTo, nullptr, nullptr, out, 3, 10);
}

// Round 5
// 276.826 us; speedup vs baseline: 1.1206x; 1.1206x over previous
//
#include <hip/hip_runtime.h>
#include <stdint.h>

#define Bq 8
#define Mq 1024
#define Hq 512
#define NHq 8
#define Dq 64
#define SPANq 1024
#define MKq 2048
#define PR2 168   // attn P-row stride (ushorts); 160 used

typedef __bf16 bf16x8 __attribute__((ext_vector_type(8)));
typedef _Float16 f16x8 __attribute__((ext_vector_type(8)));
typedef float f32x4 __attribute__((ext_vector_type(4)));
typedef unsigned short ushort8 __attribute__((ext_vector_type(8)));
typedef unsigned int uint2v __attribute__((ext_vector_type(2)));
typedef unsigned int uint4v __attribute__((ext_vector_type(4)));

static __device__ __forceinline__ unsigned short f2bf(float f) {
  union { float f; unsigned u; } x; x.f = f;
  unsigned r = x.u + 0x7FFFu + ((x.u >> 16) & 1u);
  return (unsigned short)(r >> 16);
}

static __device__ __forceinline__ unsigned pk_f16(float a, float b) {
  return __builtin_bit_cast(unsigned, __builtin_amdgcn_cvt_pkrtz(a, b));
}

// packed f32x2 -> bf16x2 (RNE), gfx940+ instruction (no builtin; see learn_hip m240)
static __device__ __forceinline__ unsigned pk_bf16(float a, float b) {
  unsigned r;
  asm("v_cvt_pk_bf16_f32 %0, %1, %2" : "=v"(r) : "v"(a), "v"(b));
  return r;
}

static __device__ __forceinline__ f32x4 mfma_bf16(bf16x8 a, bf16x8 b, f32x4 c) {
  return __builtin_amdgcn_mfma_f32_16x16x32_bf16(a, b, c, 0, 0, 0);
}
static __device__ __forceinline__ f32x4 mfma_f16(f16x8 a, f16x8 b, f32x4 c) {
  return __builtin_amdgcn_mfma_f32_16x16x32_f16(a, b, c, 0, 0, 0);
}

// async 16B/lane global->LDS DMA; lds dest = uniform base + lane*16
static __device__ __forceinline__ void async_ld16(const void* g, void* l) {
  __builtin_amdgcn_global_load_lds(
      (const __attribute__((address_space(1))) void*)g,
      (__attribute__((address_space(3))) void*)l, 16, 0, 0);
}

// ---------------- prep: transpose+convert weights (WT[o][i]=W[i][o]) and pos (posT[s][d]=pos[d][s])
__global__ __launch_bounds__(256) void prep_transpose(
    const float* __restrict__ Wq, const float* __restrict__ Wk,
    const float* __restrict__ Wv, const float* __restrict__ Wo,
    const float* __restrict__ pos,
    unsigned short* __restrict__ WTq, unsigned short* __restrict__ WTk,
    unsigned short* __restrict__ WTv, unsigned short* __restrict__ WTo,
    unsigned short* __restrict__ posT) {
  __shared__ float tile[64][65];
  const int bid = blockIdx.x;
  const float* src; unsigned short* dst;
  int src_stride, dst_stride, i0, o0;
  if (bid < 256) {
    const int w = bid >> 6, t = bid & 63;
    src = (w == 0) ? Wq : (w == 1) ? Wk : (w == 2) ? Wv : Wo;
    dst = (w == 0) ? WTq : (w == 1) ? WTk : (w == 2) ? WTv : WTo;
    src_stride = Hq; dst_stride = Hq;
    i0 = (t >> 3) * 64; o0 = (t & 7) * 64;
  } else {
    const int t = bid - 256;
    src = pos; dst = posT;
    src_stride = SPANq; dst_stride = Dq;
    i0 = 0; o0 = t * 64;
  }
  const int tid = threadIdx.x;
  for (int e = tid; e < 4096; e += 256) {
    const int r = e >> 6, c = e & 63;
    tile[r][c] = src[(size_t)(i0 + r) * src_stride + o0 + c];
  }
  __syncthreads();
  for (int e = tid; e < 4096; e += 256) {
    const int r = e >> 6, c = e & 63;
    dst[(size_t)(o0 + r) * dst_stride + i0 + c] = f2bf(tile[c][r]);
  }
}

// ---------------- 128x128 GEMM via global_load_lds staging (BK=64, XOR-swizzled)
// bf16 A input (used for out-projection, mode 3: fp32 row-major output)
__global__ __launch_bounds__(256, 2) void gemm128(
    const unsigned short* __restrict__ Xb, const unsigned short* __restrict__ WT,
    unsigned short* __restrict__ outb, _Float16* __restrict__ outv,
    float* __restrict__ outf, int mode, int tshift) {
  __shared__ unsigned short sh[18432];   // 36 KB
  unsigned short* As = sh;               // [128][64] unpadded, swizzled
  unsigned short* Bs = sh + 8192;
  const int tid = threadIdx.x;
  const int wave = tid >> 6, lane = tid & 63;
  const int q = lane >> 4, l16 = lane & 15;
  const int wy = wave >> 1, wx = wave & 1;
  const size_t m0 = (size_t)blockIdx.x * 128;
  const int n0 = blockIdx.y * 128;
  const int dsub = lane >> 3;                 // row offset within slot
  const int dswz = (lane & 7) ^ dsub;         // swizzled source chunk

  f32x4 acc[4][4] = {};

  for (int k0 = 0; k0 < Hq; k0 += 64) {
    __syncthreads();
#pragma unroll
    for (int i = 0; i < 4; i++) {
      const int s = wave * 4 + i;             // slot 0..15, 8 rows each
      const int r = s * 8 + dsub;             // row 0..127
      async_ld16(Xb + (m0 + r) * Hq + k0 + dswz * 8, As + s * 512);
      async_ld16(WT + (size_t)(n0 + r) * Hq + k0 + dswz * 8, Bs + s * 512);
    }
    __syncthreads();
    bf16x8 af[2][4], bg[2][4];
#pragma unroll
    for (int h = 0; h < 2; h++) {
#pragma unroll
      for (int mt = 0; mt < 4; mt++) {
        const int R = wy * 64 + mt * 16 + l16;
        af[h][mt] = *(const bf16x8*)(As + R * 64 + (((h * 4 + q) ^ (l16 & 7)) * 8));
      }
#pragma unroll
      for (int nt = 0; nt < 4; nt++) {
        const int R = wx * 64 + nt * 16 + l16;
        bg[h][nt] = *(const bf16x8*)(Bs + R * 64 + (((h * 4 + q) ^ (l16 & 7)) * 8));
      }
    }
#pragma unroll
    for (int h = 0; h < 2; h++)
#pragma unroll
      for (int mt = 0; mt < 4; mt++)
#pragma unroll
        for (int nt = 0; nt < 4; nt++)
          acc[mt][nt] = mfma_bf16(af[h][mt], bg[h][nt], acc[mt][nt]);
  }

  const int Tlen = 1 << tshift;
#pragma unroll
  for (int mt = 0; mt < 4; mt++) {
#pragma unroll
    for (int nt = 0; nt < 4; nt++) {
      const int c = n0 + wx * 64 + nt * 16 + l16;
#pragma unroll
      for (int r = 0; r < 4; r++) {
        const int m = (int)m0 + wy * 64 + mt * 16 + q * 4 + r;
        const float val = acc[mt][nt][r];
        if (mode == 3) {
          outf[(size_t)m * Hq + c] = val;
        } else {
          const int b = m >> tshift, t = m & (Tlen - 1);
          const int head = c >> 6, d = c & 63;
          outb[(((size_t)(b * 8 + head) << tshift) + t) * 64 + d] = f2bf(val);
        }
      }
    }
  }
}

// ---------------- fused Q/K/V projection: fp32 X staged directly (conv_bf16 eliminated)
// A tile staged as fp32 [128][64] (32 KB, 32 slots x 4 rows), swizzle on 4-float chunks:
// LDS[r][p] = src[r][p ^ (r&7)]. LDS->frag converts via v_cvt_pk_bf16_f32.
// B tile = pre-converted bf16 weights (unchanged path).
// grid (320, 4): x<64 -> Q (mode 0), x<192 -> K (mode 0), else -> V (mode 2 transpose epi).
__global__ __launch_bounds__(256, 2) void gemm_qkv(
    const float* __restrict__ qF, const float* __restrict__ kF,
    const float* __restrict__ vF,
    const unsigned short* __restrict__ WTq, const unsigned short* __restrict__ WTk,
    const unsigned short* __restrict__ WTv,
    unsigned short* __restrict__ qb, unsigned short* __restrict__ kbuf,
    _Float16* __restrict__ vTb) {
  __shared__ float shf[12288];                 // 48 KB: As fp32 32 KB + Bs bf16 16 KB
  float* As = shf;                             // [128][64] fp32, swizzled
  unsigned short* Bs = (unsigned short*)(shf + 8192);

  const int x = blockIdx.x;
  const float* Xf; const unsigned short* WT;
  unsigned short* outb = nullptr; _Float16* outv = nullptr;
  int mode, tshift, bx;
  if (x < 64)       { Xf = qF; WT = WTq; outb = qb;   mode = 0; tshift = 10; bx = x; }
  else if (x < 192) { Xf = kF; WT = WTk; outb = kbuf; mode = 0; tshift = 11; bx = x - 64; }
  else              { Xf = vF; WT = WTv; outv = vTb;  mode = 2; tshift = 11; bx = x - 192; }

  const int tid = threadIdx.x;
  const int wave = tid >> 6, lane = tid & 63;
  const int q = lane >> 4, l16 = lane & 15;
  const int wy = wave >> 1, wx = wave & 1;
  const size_t m0 = (size_t)bx * 128;
  const int n0 = blockIdx.y * 128;
  // B-side (bf16): slot covers 8 rows; lane row = lane>>3, chunk of 8 ushorts
  const int dsub = lane >> 3;
  const int dswz = (lane & 7) ^ dsub;
  // A-side (fp32): slot covers 4 rows; lane row = lane>>4, chunk of 4 floats (16 B)
  const int arow = lane >> 4;                  // 0..3 within slot
  const int apos = lane & 15;                  // chunk position 0..15

  f32x4 acc[4][4] = {};

  for (int k0 = 0; k0 < Hq; k0 += 64) {
    __syncthreads();
#pragma unroll
    for (int i = 0; i < 8; i++) {
      const int s = wave * 8 + i;              // A slot 0..31, 4 rows each
      const int r = s * 4 + arow;              // row 0..127
      const int gsw = apos ^ (((s & 1) << 2) | arow);  // = apos ^ (r&7)
      async_ld16(Xf + (m0 + r) * Hq + k0 + gsw * 4, As + s * 256);
    }
#pragma unroll
    for (int i = 0; i < 4; i++) {
      const int s = wave * 4 + i;              // B slot 0..15, 8 rows each
      const int r = s * 8 + dsub;
      async_ld16(WT + (size_t)(n0 + r) * Hq + k0 + dswz * 8, Bs + s * 512);
    }
    __syncthreads();

    bf16x8 af[2][4], bg[2][4];
#pragma unroll
    for (int h = 0; h < 2; h++) {
#pragma unroll
      for (int mt = 0; mt < 4; mt++) {
        const int R = wy * 64 + mt * 16 + l16;
        const int xr = R & 7;
        const int c0 = h * 8 + q * 2;          // 4-float chunk index (k = c0*4)
        const f32x4 a0 = *(const f32x4*)(As + R * 64 + ((c0 ^ xr) * 4));
        const f32x4 a1 = *(const f32x4*)(As + R * 64 + (((c0 + 1) ^ xr) * 4));
        uint4v w;
        w[0] = pk_bf16(a0[0], a0[1]);
        w[1] = pk_bf16(a0[2], a0[3]);
        w[2] = pk_bf16(a1[0], a1[1]);
        w[3] = pk_bf16(a1[2], a1[3]);
        af[h][mt] = __builtin_bit_cast(bf16x8, w);
      }
#pragma unroll
      for (int nt = 0; nt < 4; nt++) {
        const int R = wx * 64 + nt * 16 + l16;
        bg[h][nt] = *(const bf16x8*)(Bs + R * 64 + (((h * 4 + q) ^ (l16 & 7)) * 8));
      }
    }
#pragma unroll
    for (int h = 0; h < 2; h++)
#pragma unroll
      for (int mt = 0; mt < 4; mt++)
#pragma unroll
        for (int nt = 0; nt < 4; nt++)
          acc[mt][nt] = mfma_bf16(af[h][mt], bg[h][nt], acc[mt][nt]);
  }

  if (mode == 2) {
    __syncthreads();  // protect tile LDS before reuse
    // transpose epilogue: per-wave 64x64 tile -> vT[(b*8+head)*64 + d][t] f16
    _Float16* tr = (_Float16*)shf + wave * 4608;  // [64][72], 36 KB total
#pragma unroll
    for (int nt = 0; nt < 4; nt++)
#pragma unroll
      for (int mt = 0; mt < 4; mt++)
#pragma unroll
        for (int r = 0; r < 4; r++)
          tr[(nt * 16 + l16) * 72 + mt * 16 + q * 4 + r] = (_Float16)acc[mt][nt][r];
    const int head = blockIdx.y * 2 + wx;
    const int mrow0 = (int)m0 + wy * 64;
    const int Tlen = 1 << tshift;
    const int b = mrow0 >> tshift, t0 = mrow0 & (Tlen - 1);
#pragma unroll
    for (int it = 0; it < 8; it++) {
      const int dl = it * 8 + (lane >> 3), tl = (lane & 7) * 8;
      const f16x8 v = *(const f16x8*)(tr + dl * 72 + tl);
      *(f16x8*)(outv + ((size_t)((b * 8 + head) * 64 + dl)) * Tlen + t0 + tl) = v;
    }
    return;
  }

  const int Tlen = 1 << tshift;
#pragma unroll
  for (int mt = 0; mt < 4; mt++) {
#pragma unroll
    for (int nt = 0; nt < 4; nt++) {
      const int c = n0 + wx * 64 + nt * 16 + l16;
#pragma unroll
      for (int r = 0; r < 4; r++) {
        const int m = (int)m0 + wy * 64 + mt * 16 + q * 4 + r;
        const int b = m >> tshift, t = m & (Tlen - 1);
        const int head = c >> 6, d = c & 63;
        outb[(((size_t)(b * 8 + head) << tshift) + t) * 64 + d] = f2bf(acc[mt][nt][r]);
      }
    }
  }
}

// ---------------- banded attention: LDS-staged K+pos via swizzled DMA (r0 structure,
// the empirical best at 114.7 us). block = 64 queries x one head; wave owns 16 queries.
__global__ __launch_bounds__(256, 2) void attn3(
    const unsigned short* __restrict__ qb, const unsigned short* __restrict__ kglob,
    const _Float16* __restrict__ vT, const unsigned short* __restrict__ posT,
    unsigned short* __restrict__ ctx) {
  __shared__ unsigned short Kt[12288];          // K tile: 192 rows x 64 d (swizzled)
  __shared__ unsigned short Pt[8192];           // pos tile: 128 rows x 64 d (swizzled)
  __shared__ unsigned short Psh[4 * 16 * PR2];  // P / pos-skew rows (wave-private)

  const int tid = threadIdx.x;
  const int wave = tid >> 6, lane = tid & 63;
  const int q = lane >> 4, l16 = lane & 15;
  const int n = blockIdx.y;
  const int m0 = blockIdx.x * 64;
  const int m0w = m0 + wave * 16;
  const int dsub = lane >> 3;
  const int dswz = (lane & 7) ^ dsub;

  unsigned short* row = Psh + (wave * 16 + l16) * PR2;

  // Q fragments (B-operand): col m = l16, k = q*8+j over d
  const unsigned short* qbase = qb + ((size_t)n * Mq + m0w + l16) * Dq;
  const bf16x8 qf0 = *(const bf16x8*)(qbase + q * 8);
  const bf16x8 qf1 = *(const bf16x8*)(qbase + 32 + q * 8);

  const unsigned short* kbn = kglob + (size_t)n * MKq * Dq;
  const _Float16* vbn = vT + (size_t)n * Dq * MKq;

  f32x4 O[4] = {};
  float zrow = 0.f, mrow = -1e30f;

  for (int c = 0; c < 8; c++) {
    const int sbase = c * 128;
    const int jb = m0 + sbase;       // K tile base row (block-level)
    const int j00 = m0w + sbase;     // wave's base

    __syncthreads();  // previous chunk's tile reads complete
    // --- DMA K tile: 24 slots x 1 KB; pos tile: 16 slots
#pragma unroll
    for (int i = 0; i < 6; i++) {
      const int s = wave + 4 * i;
      const int r = s * 8 + dsub;    // 0..191
      async_ld16(kbn + (size_t)(jb + r) * Dq + dswz * 8, Kt + s * 512);
    }
#pragma unroll
    for (int i = 0; i < 4; i++) {
      const int s = wave + 4 * i;
      const int r = s * 8 + dsub;    // 0..127
      async_ld16(posT + (size_t)(sbase + r) * Dq + dswz * 8, Pt + s * 512);
    }
    __syncthreads();  // DMA drained (compiler emits vmcnt(0) before barrier)

    // --- pos logits -> skewed rows: col = 16 + s_local + m
#pragma unroll
    for (int t = 0; t < 8; t++) {
      const int rl = t * 16 + l16;
      const int ch = (q ^ (l16 & 7)) * 8;
      const bf16x8 p0 = *(const bf16x8*)(Pt + rl * 64 + ch);
      const bf16x8 p1 = *(const bf16x8*)(Pt + rl * 64 + (ch ^ 32));
      f32x4 b = {};
      b = mfma_bf16(p0, qf0, b);
      b = mfma_bf16(p1, qf1, b);
      const int cw = 16 + t * 16 + 4 * q + l16;
      row[cw + 0] = f2bf(b[0]);
      row[cw + 1] = f2bf(b[1]);
      row[cw + 2] = f2bf(b[2]);
      row[cw + 3] = f2bf(b[3]);
    }

    // --- ctx logits S^T[j][m] from K tile + skewed pos readback + band masks
    f32x4 S[9];
#pragma unroll
    for (int t = 0; t < 9; t++) {
      const int rl = wave * 16 + t * 16 + l16;  // 0..191
      const int ch = (q ^ (l16 & 7)) * 8;
      const bf16x8 k0 = *(const bf16x8*)(Kt + rl * 64 + ch);
      const bf16x8 k1 = *(const bf16x8*)(Kt + rl * 64 + (ch ^ 32));
      f32x4 a = {};
      a = mfma_bf16(k0, qf0, a);
      a = mfma_bf16(k1, qf1, a);
      const uint2v pv = *(const uint2v*)(row + 16 + t * 16 + 4 * q);
      a[0] += __uint_as_float(pv.x << 16);
      a[1] += __uint_as_float(pv.x & 0xffff0000u);
      a[2] += __uint_as_float(pv.y << 16);
      a[3] += __uint_as_float(pv.y & 0xffff0000u);
      S[t] = a;
    }
#pragma unroll
    for (int r = 0; r < 4; r++) {
      if (4 * q + r < l16) S[0][r] = -1e30f;
      if (4 * q + r >= l16) S[8][r] = -1e30f;
    }

    // --- online softmax in registers
    float mx = -1e30f;
#pragma unroll
    for (int t = 0; t < 9; t++)
      mx = fmaxf(mx, fmaxf(fmaxf(S[t][0], S[t][1]), fmaxf(S[t][2], S[t][3])));
    mx = fmaxf(mx, __shfl_xor(mx, 16, 64));
    mx = fmaxf(mx, __shfl_xor(mx, 32, 64));
    const float m_new = fmaxf(mrow, mx);
    const float alpha = __expf((mrow - m_new) * 0.125f);
    float zs = 0.f;
#pragma unroll
    for (int t = 0; t < 9; t++) {
#pragma unroll
      for (int r = 0; r < 4; r++) {
        const float e = __expf((S[t][r] - m_new) * 0.125f);
        S[t][r] = e; zs += e;
      }
    }
    zs += __shfl_xor(zs, 16, 64);
    zs += __shfl_xor(zs, 32, 64);
    zrow = zrow * alpha + zs;
    mrow = m_new;
#pragma unroll
    for (int dt = 0; dt < 4; dt++) O[dt] *= alpha;

    // --- P -> LDS f16 at [m][j_local]; zero tail [144,160)
#pragma unroll
    for (int t = 0; t < 9; t++) {
      *(unsigned*)(row + t * 16 + 4 * q) = pk_f16(S[t][0], S[t][1]);
      *(unsigned*)(row + t * 16 + 4 * q + 2) = pk_f16(S[t][2], S[t][3]);
    }
    *(unsigned*)(row + 144 + 4 * q) = 0u;
    *(unsigned*)(row + 144 + 4 * q + 2) = 0u;

    // --- PV: O^T += V^T . P^T  (V direct from global; batch all 20 loads)
    f16x8 Bf[5];
#pragma unroll
    for (int kt = 0; kt < 5; kt++)
      Bf[kt] = *(const f16x8*)(row + kt * 32 + q * 8);
    f16x8 Vv[5][4];
#pragma unroll
    for (int kt = 0; kt < 5; kt++) {
      int j = j00 + kt * 32 + q * 8;
      if (j > MKq - 8) j = MKq - 8;  // clamped cols have P==0
#pragma unroll
      for (int dt = 0; dt < 4; dt++)
        Vv[kt][dt] = *(const f16x8*)(vbn + (size_t)(dt * 16 + l16) * MKq + j);
    }
#pragma unroll
    for (int kt = 0; kt < 5; kt++)
#pragma unroll
      for (int dt = 0; dt < 4; dt++)
        O[dt] = mfma_f16(Vv[kt][dt], Bf[kt], O[dt]);
  }

  // epilogue: ctx[b*M + m][head*64 + d] = O/Z  (lane owns row m = l16)
  const float zi = 1.f / zrow;
  unsigned short* cp = ctx + ((size_t)(n >> 3) * Mq + m0w + l16) * Hq + (n & 7) * Dq;
#pragma unroll
  for (int dt = 0; dt < 4; dt++)
#pragma unroll
    for (int r = 0; r < 4; r++)
      cp[dt * 16 + q * 4 + r] = f2bf(O[dt][r] * zi);
}

extern "C" void kernel_launch(void* const* d_in, const int* in_sizes, int n_in,
                              void* d_out, int out_size, void* d_ws, size_t ws_size,
                              hipStream_t stream) {
  const float* query = (const float*)d_in[0];
  const float* key   = (const float*)d_in[1];
  const float* value = (const float*)d_in[2];
  const float* pos   = (const float*)d_in[3];
  const float* Wq    = (const float*)d_in[4];
  const float* Wk    = (const float*)d_in[5];
  const float* Wv    = (const float*)d_in[6];
  const float* Wo    = (const float*)d_in[7];
  float* out = (float*)d_out;

  char* w = (char*)d_ws;
  unsigned short* qb   = (unsigned short*)w; w += (size_t)64 * Mq * Dq * 2;    // 8 MB
  unsigned short* kbuf = (unsigned short*)w; w += (size_t)64 * MKq * Dq * 2;   // 16 MB
  _Float16*       vTb  = (_Float16*)w;       w += (size_t)64 * Dq * MKq * 2;   // 16 MB
  unsigned short* posT = (unsigned short*)w; w += (size_t)SPANq * Dq * 2;      // 128 KB
  unsigned short* WTq  = (unsigned short*)w; w += (size_t)Hq * Hq * 2;
  unsigned short* WTk  = (unsigned short*)w; w += (size_t)Hq * Hq * 2;
  unsigned short* WTv  = (unsigned short*)w; w += (size_t)Hq * Hq * 2;
  unsigned short* WTo  = (unsigned short*)w; w += (size_t)Hq * Hq * 2;
  unsigned short* ctx  = (unsigned short*)w; w += (size_t)Bq * Mq * Hq * 2;    // 8 MB

  prep_transpose<<<272, 256, 0, stream>>>(Wq, Wk, Wv, Wo, pos, WTq, WTk, WTv, WTo, posT);
  gemm_qkv<<<dim3(320, 4), 256, 0, stream>>>(query, key, value, WTq, WTk, WTv, qb, kbuf, vTb);
  attn3<<<dim3(16, 64), 256, 0, stream>>>(qb, kbuf, vTb, posT, ctx);
  gemm128<<<dim3(64, 4), 256, 0, stream>>>(ctx, WTo, nullptr, nullptr, out, 3, 10);
}